// Round 8
// baseline (349.251 us; speedup 1.0000x reference)
//
#include <hip/hip_runtime.h>
#include <math.h>

#define EPSF 1e-8f
// f32 nearest to 2*pi
#define TWO_PI_F 6.28318530717958647692f

// ---------------------------------------------------------------------------
// EXACT path (verbatim from the verified 340us kernel, absmax 0.0039).
// Only used for pixel-groups containing a hue-wrap-neighborhood pixel
// (h ~ 1.0), where the reference's atan2-roundtrip can round h' to exactly
// 1.0f -> hi==6 -> the jnp.select default ZERO output. That discontinuity
// must be replicated bit-faithfully; everywhere else the roundtrip is
// algebraically the identity.
// ---------------------------------------------------------------------------
__device__ __forceinline__ void hvi_exact(float r, float g, float b, float k,
                                          float& ro, float& go, float& bo)
{
    float value = fmaxf(r, fmaxf(g, b));
    float vmin  = fminf(r, fminf(g, b));
    float diff  = value - vmin + EPSF;

    bool isR = (r == value);
    bool isG = (!isR) && (g == value);

    float num  = isR ? (g - b) : (isG ? (b - r) : (r - g));
    float offs = isR ? 0.0f   : (isG ? 2.0f    : 4.0f);
    float x    = num / diff;                 // IEEE divide (matches np)
    float hue6 = offs + x;
    if (isR && x < 0.0f) hue6 = x + 6.0f;    // np mod semantics
    if (vmin == value)   hue6 = 0.0f;
    float hue = hue6 / 6.0f;                 // 6.0/6.0 == 1.0 exactly

    float sat = (value == 0.0f) ? 0.0f : (value - vmin) / (value + EPSF);

    float sv = __sinf((value * 0.5f) * 3.14159265358979323846f) + EPSF;
    float cs = __expf(k * __logf(sv));

    float ang = TWO_PI_F * hue;
    float sh, ch;
    sincosf(ang, &sh, &ch);                  // precise libm

    float X = cs * sat * ch;
    float Y = cs * sat * sh;

    // ---- _phvit ----
    float H = fminf(fmaxf(X, -1.0f), 1.0f);
    float V = fminf(fmaxf(Y, -1.0f), 1.0f);
    float v = fminf(fmaxf(value, 0.0f), 1.0f);

    float csd = cs + EPSF;
    H = fminf(fmaxf(H / csd, -1.0f), 1.0f);
    V = fminf(fmaxf(V / csd, -1.0f), 1.0f);

    float t2 = atan2f(V, H) / TWO_PI_F;      // precise atan2 + IEEE divide
    float h  = (t2 < 0.0f) ? t2 + 1.0f : t2; // np mod(x, 1.0) -> can hit 1.0f
    float s  = fminf(fmaxf(sqrtf(H * H + V * V), 0.0f), 1.0f);

    float h6  = h * 6.0f;
    float hif = floorf(h6);
    float f   = h6 - hif;
    float pv  = v * (1.0f - s);
    float qv  = v * (1.0f - f * s);
    float tv  = v * (1.0f - (1.0f - f) * s);
    int hi = (int)hif;

    float rr = 0.0f, gg = 0.0f, bb = 0.0f;   // hi==6 falls through to zero
    rr = (hi == 0) ? v  : rr;  gg = (hi == 0) ? tv : gg;  bb = (hi == 0) ? pv : bb;
    rr = (hi == 1) ? qv : rr;  gg = (hi == 1) ? v  : gg;  bb = (hi == 1) ? pv : bb;
    rr = (hi == 2) ? pv : rr;  gg = (hi == 2) ? v  : gg;  bb = (hi == 2) ? tv : bb;
    rr = (hi == 3) ? pv : rr;  gg = (hi == 3) ? qv : gg;  bb = (hi == 3) ? v  : bb;
    rr = (hi == 4) ? tv : rr;  gg = (hi == 4) ? pv : gg;  bb = (hi == 4) ? v  : bb;
    rr = (hi == 5) ? v  : rr;  gg = (hi == 5) ? pv : gg;  bb = (hi == 5) ? qv : bb;

    ro = rr; go = gg; bo = bb;
}

// ---------------------------------------------------------------------------
// FAST path (algebraic identity roundtrip): p = vmin (exact), q = v - sv*f,
// t = vmin + sv*f; only discontinuity is the h'==1.0 wrap -> zero output,
// routed to the exact path by the band check.
// ---------------------------------------------------------------------------
#define BAND_THRESH 5.99998f

// 16 px/thread, STREAM-MAJOR register staging:
//   loads:  4 consecutive dwordx4 per stream (4 KB contiguous burst per wave
//           per stream), all 12 issued before any use -> 12 KB in flight/wave
//   compute: in-place overwrite of the input registers (48 data VGPRs total;
//           the rare band path RELOADS inputs from global instead of keeping
//           a second copy alive)
//   stores: stream-major, 4 consecutive dwordx4 per stream
// vs r7 (2 KB burst, 6 KB in flight, ~13 waves/CU): 2x burst granularity,
// 2x MLP, and lower VGPR/thread-count pressure -> higher occupancy.
extern "C" __global__ void __launch_bounds__(256)
rgb_hvi_kernel(const float* __restrict__ img, const float* __restrict__ kptr,
               float* __restrict__ out, int nthreads)
{
    int i = blockIdx.x * blockDim.x + threadIdx.x;
    if (i >= nthreads) return;
    const float k = kptr[0];

    unsigned int q = (unsigned int)i << 4;        // first pixel of 16
    unsigned int n = q >> 20;                     // image index
    unsigned int p = q & 1048575u;                // pixel within image
    size_t base = (size_t)n * 3145728u + p;

    float d[3][16];                               // d[0]=R, d[1]=G, d[2]=B

    // Stream-major load bursts, all issued before first use.
#pragma unroll
    for (int c = 0; c < 3; ++c) {
        const float4* P = reinterpret_cast<const float4*>(img + base + (size_t)c * 1048576u);
#pragma unroll
        for (int w = 0; w < 4; ++w) {
            float4 t = P[w];
            d[c][4*w+0] = t.x; d[c][4*w+1] = t.y;
            d[c][4*w+2] = t.z; d[c][4*w+3] = t.w;
        }
    }

    bool band = false;
#pragma unroll
    for (int j = 0; j < 16; ++j) {
        float r = d[0][j], g = d[1][j], b = d[2][j];

        float value = fmaxf(r, fmaxf(g, b));      // v_max3
        float vmin  = fminf(r, fminf(g, b));      // v_min3
        float sv    = value - vmin;

        bool isR = (r == value);
        bool isG = (!isR) && (g == value);

        float num  = isR ? (g - b) : (isG ? (b - r) : (r - g));
        float offs = isR ? 0.0f   : (isG ? 2.0f    : 4.0f);
        float x    = num * __builtin_amdgcn_rcpf(sv + EPSF);
        float h6   = offs + x;
        if (isR && x < 0.0f) h6 = x + 6.0f;       // np mod semantics (wrap)
        if (vmin == value)   h6 = 0.0f;

        band = band || (h6 > BAND_THRESH);

        float hif = floorf(h6);
        float f   = h6 - hif;
        int   hi  = (int)hif;                     // in [0,5] off-band

        float svf = sv * f;
        float v   = value;
        float pv  = vmin;                         // v*(1-s)
        float qv  = value - svf;                  // v*(1-f*s)
        float tv  = vmin + svf;                   // v*(1-(1-f)*s)

        d[0][j] = (hi == 0) ? v  : (hi == 1) ? qv : (hi == 2) ? pv
                : (hi == 3) ? pv : (hi == 4) ? tv : v;
        d[1][j] = (hi == 0) ? tv : (hi == 1) ? v  : (hi == 2) ? v
                : (hi == 3) ? qv : (hi == 4) ? pv : pv;
        d[2][j] = (hi == 0) ? pv : (hi == 1) ? pv : (hi == 2) ? tv
                : (hi == 3) ? v  : (hi == 4) ? v  : qv;
    }

    // Cold block: reload inputs from global (L2-hot) and recompute the whole
    // group with the bit-faithful exact path. Keeps no second register copy
    // alive in the hot path.
    if (__builtin_expect(band, 0)) {
#pragma unroll
        for (int j = 0; j < 16; ++j) {
            float r = img[base + j];
            float g = img[base + 1048576u + j];
            float b = img[base + 2097152u + j];
            hvi_exact(r, g, b, k, d[0][j], d[1][j], d[2][j]);
        }
    }

    // Stream-major store bursts.
#pragma unroll
    for (int c = 0; c < 3; ++c) {
        float4* P = reinterpret_cast<float4*>(out + base + (size_t)c * 1048576u);
#pragma unroll
        for (int w = 0; w < 4; ++w)
            P[w] = make_float4(d[c][4*w+0], d[c][4*w+1], d[c][4*w+2], d[c][4*w+3]);
    }
}

extern "C" void kernel_launch(void* const* d_in, const int* in_sizes, int n_in,
                              void* d_out, int out_size, void* d_ws, size_t ws_size,
                              hipStream_t stream)
{
    const float* img  = (const float*)d_in[0];
    const float* kptr = (const float*)d_in[1];
    float* out = (float*)d_out;

    int total    = in_sizes[0];       // 16*3*1024*1024 = 50331648
    int nthreads = total / 48;        // pixels/16 = 1048576
    int block    = 256;
    int grid     = (nthreads + block - 1) / block;   // 4096

    rgb_hvi_kernel<<<grid, block, 0, stream>>>(img, kptr, out, nthreads);
}